// Round 1
// baseline (173.210 us; speedup 1.0000x reference)
//
#include <hip/hip_runtime.h>

#define EMBED 256
#define NPOS  2304   // 48*48
#define BATCH 4
#define NH    8
#define DH    32

typedef float f32x4  __attribute__((ext_vector_type(4)));
typedef short bf16x8 __attribute__((ext_vector_type(8)));
typedef short s16x4  __attribute__((ext_vector_type(4)));

static __device__ __forceinline__ short f2b(float f) {
    union { float f; unsigned u; } c; c.f = f;
    unsigned r = (c.u + 0x7FFFu + ((c.u >> 16) & 1u)) >> 16;
    return (short)r;
}

// ---------------- kernel 1: pack weights to bf16 ----------------
// wqkv[768][256] = concat(wq, wk, wv) rows; wob[256][256]
__global__ __launch_bounds__(256) void prep_weights(
        const float* __restrict__ wq, const float* __restrict__ wk,
        const float* __restrict__ wv, const float* __restrict__ wo,
        short* __restrict__ wqkv, short* __restrict__ wob) {
    int g = blockIdx.x * 256 + threadIdx.x;
    if (g < 196608) {
        int j = g >> 8, kk = g & 255;
        int proj = j >> 8, jj = j & 255;
        const float* s = (proj == 0) ? wq : (proj == 1) ? wk : wv;
        wqkv[g] = f2b(s[jj * 256 + kk]);
    } else if (g < 262144) {
        int h2 = g - 196608;
        wob[h2] = f2b(wo[h2]);
    }
}

// ---------------- kernel 2: xs = transpose(x) + PE, bf16 ----------------
// x [b][c][n] fp32 -> xs [b][n][c] bf16
__global__ __launch_bounds__(256) void build_xs(
        const float* __restrict__ x, short* __restrict__ xs) {
    __shared__ float xt[32][65];
    int bx = blockIdx.x;
    int b = bx / 288, rem = bx % 288;
    int c0 = (rem / 36) * 32, pos0 = (rem % 36) * 64;
    int t = threadIdx.x;
    int j = t & 63, i0 = t >> 6;
    const float* xp = x + (size_t)(b * EMBED + c0) * NPOS + pos0;
#pragma unroll
    for (int rr = 0; rr < 8; ++rr) {
        int i = rr * 4 + i0;
        xt[i][j] = xp[(size_t)i * NPOS + j];
    }
    __syncthreads();
    int ii = (t & 15) * 2, jj0 = t >> 4;
    const float kln = -0.07195578415606394f;  // -ln(10000)/128
#pragma unroll
    for (int pp = 0; pp < 4; ++pp) {
        int jj = pp * 16 + jj0;
        int pos = pos0 + jj;
        float v0 = xt[ii][jj], v1 = xt[ii + 1][jj];
        float pe0 = 0.f, pe1 = 0.f;
        if (pos > 0) {
            int c = c0 + ii;
            float a0 = (float)pos * __expf((float)c * kln);
            float a1 = (float)pos * __expf((float)(c + 1) * kln);
            pe0 = sinf(a0);   // even col -> sin
            pe1 = cosf(a1);   // odd col -> cos
        }
        unsigned lo = (unsigned short)f2b(v0 + pe0);
        unsigned hi = (unsigned short)f2b(v1 + pe1);
        *reinterpret_cast<unsigned*>(xs + (size_t)(b * NPOS + pos) * EMBED + c0 + ii) =
            lo | (hi << 16);
    }
}

// ---------------- kernel 3: QKV GEMM ----------------
// A = xs bf16 [9216][256], B = wqkv bf16 [768][256] (K-contig)
// q[b][h][n][dh] (scaled 1/sqrt(dh)), k[b][h][n][dh], vt[b][h][dh][n], all bf16
__global__ __launch_bounds__(256) void gemm_qkv(
        const short* __restrict__ A, const short* __restrict__ B,
        const float* __restrict__ bq, const float* __restrict__ bk,
        const float* __restrict__ bv,
        short* __restrict__ qd, short* __restrict__ kd, short* __restrict__ vtd) {
    __shared__ short a_sm[128 * 32];
    __shared__ short b_sm[128 * 32];
    int bx = blockIdx.x;
    int bm = bx / 6, bn = bx % 6;
    int m0 = bm * 128, n0 = bn * 128;
    int t = threadIdx.x;
    int lane = t & 63, wid = t >> 6;
    int wm = wid >> 1, wn = wid & 1;
    int l15 = lane & 15, l4 = lane >> 4;

    f32x4 zero = {0.f, 0.f, 0.f, 0.f};
    f32x4 acc[4][4];
#pragma unroll
    for (int mi = 0; mi < 4; ++mi)
#pragma unroll
        for (int ni = 0; ni < 4; ++ni) acc[mi][ni] = zero;

    for (int ks = 0; ks < 8; ++ks) {
        __syncthreads();
#pragma unroll
        for (int pass = 0; pass < 2; ++pass) {
            int idx = t + pass * 256;
            int row = idx >> 2, slot = idx & 3;
            int sw = slot ^ ((row >> 1) & 3);
            *(bf16x8*)&a_sm[row * 32 + sw * 8] =
                *(const bf16x8*)&A[(size_t)(m0 + row) * 256 + ks * 32 + slot * 8];
            *(bf16x8*)&b_sm[row * 32 + sw * 8] =
                *(const bf16x8*)&B[(size_t)(n0 + row) * 256 + ks * 32 + slot * 8];
        }
        __syncthreads();
        bf16x8 af[4], bfr[4];
#pragma unroll
        for (int mi = 0; mi < 4; ++mi) {
            int ar = wm * 64 + mi * 16 + l15;
            af[mi] = *(const bf16x8*)&a_sm[ar * 32 + ((l4 ^ ((ar >> 1) & 3)) * 8)];
        }
#pragma unroll
        for (int ni = 0; ni < 4; ++ni) {
            int br = wn * 64 + ni * 16 + l15;
            bfr[ni] = *(const bf16x8*)&b_sm[br * 32 + ((l4 ^ ((br >> 1) & 3)) * 8)];
        }
#pragma unroll
        for (int mi = 0; mi < 4; ++mi)
#pragma unroll
            for (int ni = 0; ni < 4; ++ni)
                acc[mi][ni] = __builtin_amdgcn_mfma_f32_16x16x32_bf16(
                    af[mi], bfr[ni], acc[mi][ni], 0, 0, 0);
    }

    const float rs = 0.17677669529663687f;  // 1/sqrt(32)
#pragma unroll
    for (int mi = 0; mi < 4; ++mi) {
        int rowb = m0 + wm * 64 + mi * 16 + l4 * 4;
        int b = rowb / NPOS;
        int pos = rowb - b * NPOS;
#pragma unroll
        for (int ni = 0; ni < 4; ++ni) {
            int jcol = n0 + wn * 64 + ni * 16 + l15;
            int proj = jcol >> 8, jj = jcol & 255;
            int h = jj >> 5, d = jj & 31;
            float bias = ((proj == 0) ? bq : (proj == 1) ? bk : bv)[jj];
            if (proj == 2) {
                s16x4 pk;
#pragma unroll
                for (int r = 0; r < 4; ++r) pk[r] = f2b(acc[mi][ni][r] + bias);
                *(s16x4*)&vtd[((size_t)(b * NH + h) * DH + d) * NPOS + pos] = pk;
            } else {
                short* dst = (proj == 0) ? qd : kd;
                float sc = (proj == 0) ? rs : 1.0f;
#pragma unroll
                for (int r = 0; r < 4; ++r)
                    dst[((size_t)(b * NH + h) * NPOS + pos + r) * DH + d] =
                        f2b((acc[mi][ni][r] + bias) * sc);
            }
        }
    }
}

// ---------------- kernel 4: flash attention ----------------
// Q,K [bh][n][dh] bf16 (Q pre-scaled), VT [bh][dh][n] bf16 -> AO [b][n][c] bf16
__global__ __launch_bounds__(256) void attn_fwd(
        const short* __restrict__ Q, const short* __restrict__ K,
        const short* __restrict__ VT, short* __restrict__ AO) {
    __shared__ short k_sm[64 * 32];
    __shared__ short vt_sm[32 * 64];
    __shared__ short p_sm[4 * 16 * 64];
    int bx = blockIdx.x;
    int bh = bx / 36, qt = bx % 36;
    int q0 = qt * 64;
    int t = threadIdx.x, lane = t & 63, wid = t >> 6;
    int l15 = lane & 15, l4 = lane >> 4;

    int qrow = q0 + wid * 16 + l15;
    bf16x8 qf = *(const bf16x8*)&Q[((size_t)bh * NPOS + qrow) * DH + l4 * 8];

    float mrun[4], lrun[4];
    f32x4 zero = {0.f, 0.f, 0.f, 0.f};
    f32x4 o0 = zero, o1 = zero;
#pragma unroll
    for (int r = 0; r < 4; ++r) { mrun[r] = -1e30f; lrun[r] = 0.f; }
    short* pw = p_sm + wid * 1024;

    for (int kt = 0; kt < 36; ++kt) {
        int kv0 = kt * 64;
        __syncthreads();
        {
            int row = t >> 2, slot = t & 3;
            *(bf16x8*)&k_sm[row * 32 + ((slot ^ ((row >> 1) & 3)) * 8)] =
                *(const bf16x8*)&K[((size_t)bh * NPOS + kv0 + row) * DH + slot * 8];
            int vr = t >> 3, vs = t & 7;
            *(bf16x8*)&vt_sm[vr * 64 + ((vs ^ (vr & 7)) * 8)] =
                *(const bf16x8*)&VT[((size_t)bh * DH + vr) * NPOS + kv0 + vs * 8];
        }
        __syncthreads();

        f32x4 s[4];
#pragma unroll
        for (int sub = 0; sub < 4; ++sub) {
            int key = sub * 16 + l15;
            bf16x8 kf = *(const bf16x8*)&k_sm[key * 32 + ((l4 ^ ((key >> 1) & 3)) * 8)];
            s[sub] = __builtin_amdgcn_mfma_f32_16x16x32_bf16(qf, kf, zero, 0, 0, 0);
        }

        float Mn[4];
#pragma unroll
        for (int r = 0; r < 4; ++r) {
            float tm = fmaxf(fmaxf(s[0][r], s[1][r]), fmaxf(s[2][r], s[3][r]));
            tm = fmaxf(tm, __shfl_xor(tm, 1));
            tm = fmaxf(tm, __shfl_xor(tm, 2));
            tm = fmaxf(tm, __shfl_xor(tm, 4));
            tm = fmaxf(tm, __shfl_xor(tm, 8));
            Mn[r] = fmaxf(mrun[r], tm);
        }
        float pv[4][4];
#pragma unroll
        for (int r = 0; r < 4; ++r) {
            float ps = 0.f;
#pragma unroll
            for (int sub = 0; sub < 4; ++sub) {
                float p = __expf(s[sub][r] - Mn[r]);
                pv[sub][r] = p;
                ps += p;
            }
            ps += __shfl_xor(ps, 1);
            ps += __shfl_xor(ps, 2);
            ps += __shfl_xor(ps, 4);
            ps += __shfl_xor(ps, 8);
            float sc = __expf(mrun[r] - Mn[r]);
            lrun[r] = lrun[r] * sc + ps;
            mrun[r] = Mn[r];
            o0[r] *= sc;
            o1[r] *= sc;
        }
        // P -> LDS (per-wave region, swizzled)
#pragma unroll
        for (int sub = 0; sub < 4; ++sub) {
#pragma unroll
            for (int r = 0; r < 4; ++r) {
                int qp = l4 * 4 + r;
                int kk2 = sub * 16 + l15;
                int slot = kk2 >> 3;
                pw[qp * 64 + ((slot ^ (qp & 7)) * 8) + (kk2 & 7)] = f2b(pv[sub][r]);
            }
        }
        // PV
#pragma unroll
        for (int ko = 0; ko < 2; ++ko) {
            int slotp = l4 + ko * 4;
            bf16x8 pa = *(const bf16x8*)&pw[l15 * 64 + ((slotp ^ (l15 & 7)) * 8)];
            int d0 = l15;
            bf16x8 vf0 = *(const bf16x8*)&vt_sm[d0 * 64 + ((slotp ^ (d0 & 7)) * 8)];
            o0 = __builtin_amdgcn_mfma_f32_16x16x32_bf16(pa, vf0, o0, 0, 0, 0);
            int d1 = 16 + l15;
            bf16x8 vf1 = *(const bf16x8*)&vt_sm[d1 * 64 + ((slotp ^ (d1 & 7)) * 8)];
            o1 = __builtin_amdgcn_mfma_f32_16x16x32_bf16(pa, vf1, o1, 0, 0, 0);
        }
    }

    int b = bh >> 3, h = bh & 7;
#pragma unroll
    for (int r = 0; r < 4; ++r) {
        int qp = l4 * 4 + r;
        int grow = q0 + wid * 16 + qp;
        float inv = 1.0f / lrun[r];
        AO[((size_t)b * NPOS + grow) * EMBED + h * DH + l15] = f2b(o0[r] * inv);
        AO[((size_t)b * NPOS + grow) * EMBED + h * DH + 16 + l15] = f2b(o1[r] * inv);
    }
}

// ---------------- kernel 5: out projection + transpose ----------------
// A = ao bf16 [9216][256], B = wob bf16 [256][256] -> out fp32 [b][c][n]
__global__ __launch_bounds__(256) void gemm_out(
        const short* __restrict__ A, const short* __restrict__ B,
        const float* __restrict__ bo, float* __restrict__ out) {
    __shared__ short a_sm[128 * 32];
    __shared__ short b_sm[128 * 32];
    int bx = blockIdx.x;
    int bm = bx / 2, bn = bx % 2;
    int m0 = bm * 128, n0 = bn * 128;
    int t = threadIdx.x;
    int lane = t & 63, wid = t >> 6;
    int wm = wid >> 1, wn = wid & 1;
    int l15 = lane & 15, l4 = lane >> 4;

    f32x4 zero = {0.f, 0.f, 0.f, 0.f};
    f32x4 acc[4][4];
#pragma unroll
    for (int mi = 0; mi < 4; ++mi)
#pragma unroll
        for (int ni = 0; ni < 4; ++ni) acc[mi][ni] = zero;

    for (int ks = 0; ks < 8; ++ks) {
        __syncthreads();
#pragma unroll
        for (int pass = 0; pass < 2; ++pass) {
            int idx = t + pass * 256;
            int row = idx >> 2, slot = idx & 3;
            int sw = slot ^ ((row >> 1) & 3);
            *(bf16x8*)&a_sm[row * 32 + sw * 8] =
                *(const bf16x8*)&A[(size_t)(m0 + row) * 256 + ks * 32 + slot * 8];
            *(bf16x8*)&b_sm[row * 32 + sw * 8] =
                *(const bf16x8*)&B[(size_t)(n0 + row) * 256 + ks * 32 + slot * 8];
        }
        __syncthreads();
        bf16x8 af[4], bfr[4];
#pragma unroll
        for (int mi = 0; mi < 4; ++mi) {
            int ar = wm * 64 + mi * 16 + l15;
            af[mi] = *(const bf16x8*)&a_sm[ar * 32 + ((l4 ^ ((ar >> 1) & 3)) * 8)];
        }
#pragma unroll
        for (int ni = 0; ni < 4; ++ni) {
            int br = wn * 64 + ni * 16 + l15;
            bfr[ni] = *(const bf16x8*)&b_sm[br * 32 + ((l4 ^ ((br >> 1) & 3)) * 8)];
        }
#pragma unroll
        for (int mi = 0; mi < 4; ++mi)
#pragma unroll
            for (int ni = 0; ni < 4; ++ni)
                acc[mi][ni] = __builtin_amdgcn_mfma_f32_16x16x32_bf16(
                    af[mi], bfr[ni], acc[mi][ni], 0, 0, 0);
    }

#pragma unroll
    for (int mi = 0; mi < 4; ++mi) {
        int rowb = m0 + wm * 64 + mi * 16 + l4 * 4;
        int b = rowb / NPOS;
        int pos = rowb - b * NPOS;
#pragma unroll
        for (int ni = 0; ni < 4; ++ni) {
            int jcol = n0 + wn * 64 + ni * 16 + l15;
            float bias = bo[jcol];
            f32x4 v;
#pragma unroll
            for (int r = 0; r < 4; ++r) v[r] = acc[mi][ni][r] + bias;
            *(f32x4*)&out[((size_t)(b * EMBED) + jcol) * NPOS + pos] = v;
        }
    }
}

extern "C" void kernel_launch(void* const* d_in, const int* in_sizes, int n_in,
                              void* d_out, int out_size, void* d_ws, size_t ws_size,
                              hipStream_t stream) {
    const float* x  = (const float*)d_in[0];
    const float* wq = (const float*)d_in[1];
    const float* bq = (const float*)d_in[2];
    const float* wk = (const float*)d_in[3];
    const float* bk = (const float*)d_in[4];
    const float* wv = (const float*)d_in[5];
    const float* bv = (const float*)d_in[6];
    const float* wo = (const float*)d_in[7];
    const float* bo = (const float*)d_in[8];

    char* ws = (char*)d_ws;
    short* wqkv = (short*)(ws);               // 768*256*2   = 393216
    short* wob  = (short*)(ws + 393216);      // 256*256*2   = 131072
    short* xs   = (short*)(ws + 524288);      // 9216*256*2  = 4718592
    short* qb   = (short*)(ws + 5242880);     // 4718592
    short* kb   = (short*)(ws + 9961472);     // 4718592
    short* vtb  = (short*)(ws + 14680064);    // 4718592
    short* ao   = (short*)(ws + 19398656);    // 4718592 -> total 24117248
    float* out  = (float*)d_out;

    hipLaunchKernelGGL(prep_weights, dim3(1024), dim3(256), 0, stream, wq, wk, wv, wo, wqkv, wob);
    hipLaunchKernelGGL(build_xs,     dim3(1152), dim3(256), 0, stream, x, xs);
    hipLaunchKernelGGL(gemm_qkv,     dim3(432),  dim3(256), 0, stream, xs, wqkv, bq, bk, bv, qb, kb, vtb);
    hipLaunchKernelGGL(attn_fwd,     dim3(1152), dim3(256), 0, stream, qb, kb, vtb, ao);
    hipLaunchKernelGGL(gemm_out,     dim3(144),  dim3(256), 0, stream, ao, wob, bo, out);
}

// Round 2
// 95.978 us; speedup vs baseline: 1.8047x; 1.8047x over previous
//
#include <hip/hip_runtime.h>

#define EMBED 256
#define NPOS  2304   // 48*48
#define BATCH 4
#define NH    8
#define DH    32

typedef float f32x4  __attribute__((ext_vector_type(4)));
typedef short bf16x8 __attribute__((ext_vector_type(8)));
typedef short s16x4  __attribute__((ext_vector_type(4)));

static __device__ __forceinline__ short f2b(float f) {
    union { float f; unsigned u; } c; c.f = f;
    unsigned r = (c.u + 0x7FFFu + ((c.u >> 16) & 1u)) >> 16;
    return (short)r;
}

static __device__ __forceinline__ unsigned cvtpk(float lo, float hi) {
    unsigned r;
    asm("v_cvt_pk_bf16_f32 %0, %1, %2" : "=v"(r) : "v"(lo), "v"(hi));
    return r;
}

static __device__ __forceinline__ void gl_lds16(const short* g, short* l) {
    __builtin_amdgcn_global_load_lds(
        (const __attribute__((address_space(1))) unsigned int*)(g),
        (__attribute__((address_space(3))) unsigned int*)(l),
        16, 0, 0);
}

// ---------------- kernel 1: pack weights to bf16 ----------------
__global__ __launch_bounds__(256) void prep_weights(
        const float* __restrict__ wq, const float* __restrict__ wk,
        const float* __restrict__ wv, const float* __restrict__ wo,
        short* __restrict__ wqkv, short* __restrict__ wob) {
    int g = blockIdx.x * 256 + threadIdx.x;
    if (g < 196608) {
        int j = g >> 8, kk = g & 255;
        int proj = j >> 8, jj = j & 255;
        const float* s = (proj == 0) ? wq : (proj == 1) ? wk : wv;
        wqkv[g] = f2b(s[jj * 256 + kk]);
    } else if (g < 262144) {
        int h2 = g - 196608;
        wob[h2] = f2b(wo[h2]);
    }
}

// ---------------- kernel 2: xs = transpose(x) + PE, bf16 ----------------
__global__ __launch_bounds__(256) void build_xs(
        const float* __restrict__ x, short* __restrict__ xs) {
    __shared__ float xt[32][65];
    int bx = blockIdx.x;
    int b = bx / 288, rem = bx % 288;
    int c0 = (rem / 36) * 32, pos0 = (rem % 36) * 64;
    int t = threadIdx.x;
    int j = t & 63, i0 = t >> 6;
    const float* xp = x + (size_t)(b * EMBED + c0) * NPOS + pos0;
#pragma unroll
    for (int rr = 0; rr < 8; ++rr) {
        int i = rr * 4 + i0;
        xt[i][j] = xp[(size_t)i * NPOS + j];
    }
    __syncthreads();
    int ii = (t & 15) * 2, jj0 = t >> 4;
    const float kln = -0.07195578415606394f;  // -ln(10000)/128
#pragma unroll
    for (int pp = 0; pp < 4; ++pp) {
        int jj = pp * 16 + jj0;
        int pos = pos0 + jj;
        float v0 = xt[ii][jj], v1 = xt[ii + 1][jj];
        float pe0 = 0.f, pe1 = 0.f;
        if (pos > 0) {
            int c = c0 + ii;
            float a0 = (float)pos * __expf((float)c * kln);
            float a1 = (float)pos * __expf((float)(c + 1) * kln);
            pe0 = sinf(a0);
            pe1 = cosf(a1);
        }
        unsigned lo = (unsigned short)f2b(v0 + pe0);
        unsigned hi = (unsigned short)f2b(v1 + pe1);
        *reinterpret_cast<unsigned*>(xs + (size_t)(b * NPOS + pos) * EMBED + c0 + ii) =
            lo | (hi << 16);
    }
}

// ---------------- kernel 3: QKV GEMM ----------------
__global__ __launch_bounds__(256) void gemm_qkv(
        const short* __restrict__ A, const short* __restrict__ B,
        const float* __restrict__ bq, const float* __restrict__ bk,
        const float* __restrict__ bv,
        short* __restrict__ qd, short* __restrict__ kd, short* __restrict__ vtd) {
    __shared__ short a_sm[128 * 32];
    __shared__ short b_sm[128 * 32];
    int bx = blockIdx.x;
    int bm = bx / 6, bn = bx % 6;
    int m0 = bm * 128, n0 = bn * 128;
    int t = threadIdx.x;
    int lane = t & 63, wid = t >> 6;
    int wm = wid >> 1, wn = wid & 1;
    int l15 = lane & 15, l4 = lane >> 4;

    f32x4 zero = {0.f, 0.f, 0.f, 0.f};
    f32x4 acc[4][4];
#pragma unroll
    for (int mi = 0; mi < 4; ++mi)
#pragma unroll
        for (int ni = 0; ni < 4; ++ni) acc[mi][ni] = zero;

    for (int ks = 0; ks < 8; ++ks) {
        __syncthreads();
#pragma unroll
        for (int pass = 0; pass < 2; ++pass) {
            int idx = t + pass * 256;
            int row = idx >> 2, slot = idx & 3;
            int sw = slot ^ ((row >> 1) & 3);
            *(bf16x8*)&a_sm[row * 32 + sw * 8] =
                *(const bf16x8*)&A[(size_t)(m0 + row) * 256 + ks * 32 + slot * 8];
            *(bf16x8*)&b_sm[row * 32 + sw * 8] =
                *(const bf16x8*)&B[(size_t)(n0 + row) * 256 + ks * 32 + slot * 8];
        }
        __syncthreads();
        bf16x8 af[4], bfr[4];
#pragma unroll
        for (int mi = 0; mi < 4; ++mi) {
            int ar = wm * 64 + mi * 16 + l15;
            af[mi] = *(const bf16x8*)&a_sm[ar * 32 + ((l4 ^ ((ar >> 1) & 3)) * 8)];
        }
#pragma unroll
        for (int ni = 0; ni < 4; ++ni) {
            int br = wn * 64 + ni * 16 + l15;
            bfr[ni] = *(const bf16x8*)&b_sm[br * 32 + ((l4 ^ ((br >> 1) & 3)) * 8)];
        }
#pragma unroll
        for (int mi = 0; mi < 4; ++mi)
#pragma unroll
            for (int ni = 0; ni < 4; ++ni)
                acc[mi][ni] = __builtin_amdgcn_mfma_f32_16x16x32_bf16(
                    af[mi], bfr[ni], acc[mi][ni], 0, 0, 0);
    }

    const float rs = 0.17677669529663687f;  // 1/sqrt(32)
#pragma unroll
    for (int mi = 0; mi < 4; ++mi) {
        int rowb = m0 + wm * 64 + mi * 16 + l4 * 4;
        int b = rowb / NPOS;
        int pos = rowb - b * NPOS;
#pragma unroll
        for (int ni = 0; ni < 4; ++ni) {
            int jcol = n0 + wn * 64 + ni * 16 + l15;
            int proj = jcol >> 8, jj = jcol & 255;
            int h = jj >> 5, d = jj & 31;
            float bias = ((proj == 0) ? bq : (proj == 1) ? bk : bv)[jj];
            if (proj == 2) {
                s16x4 pk;
#pragma unroll
                for (int r = 0; r < 4; ++r) pk[r] = f2b(acc[mi][ni][r] + bias);
                *(s16x4*)&vtd[((size_t)(b * NH + h) * DH + d) * NPOS + pos] = pk;
            } else {
                short* dst = (proj == 0) ? qd : kd;
                float sc = (proj == 0) ? rs : 1.0f;
#pragma unroll
                for (int r = 0; r < 4; ++r)
                    dst[((size_t)(b * NH + h) * NPOS + pos + r) * DH + d] =
                        f2b((acc[mi][ni][r] + bias) * sc);
            }
        }
    }
}

// ---------------- kernel 4: flash attention (swapped QK^T, static max) ----------------
// Q,K [bh][n][dh] bf16 (Q pre-scaled by 1/sqrt(dh)), VT [bh][dh][n] bf16 -> AO [b][n][c] bf16
__global__ __launch_bounds__(256) void attn_fwd(
        const short* __restrict__ Q, const short* __restrict__ K,
        const short* __restrict__ VT, short* __restrict__ AO) {
    __shared__ short k_sm[2][64 * 32];    // [buf][key][dh], 16B blocks swizzled: blk ^ ((key>>1)&3)
    __shared__ short vt_sm[2][32 * 64];   // [buf][d][key],  16B blocks swizzled: blk ^ (d&7)
    __shared__ short p_sm[4 * 16 * 64];   // per-wave [qrow][key], 16B blocks swizzled: blk ^ (qrow&7)

    int bx0 = blockIdx.x;
    int bx = (bx0 & 7) * 144 + (bx0 >> 3);   // XCD-contiguous: same bh -> same XCD
    int bh = bx / 36, qt = bx % 36;
    int q0 = qt * 64;
    int t = threadIdx.x, lane = t & 63, wid = t >> 6;
    int l15 = lane & 15, l4 = lane >> 4;

    // Q as B-frag: col(l15)=qrow, k(l4*8..)=dh
    int qrow = q0 + wid * 16 + l15;
    bf16x8 qf = *(const bf16x8*)&Q[((size_t)bh * NPOS + qrow) * DH + l4 * 8];

    // staging source addresses (pre-swizzled so LDS dest stays linear)
    int krow = t >> 2, kblk = t & 3;
    const short* kg = &K[((size_t)bh * NPOS + krow) * DH + ((kblk ^ ((krow >> 1) & 3)) * 8)];
    int vrow = t >> 3, vblk = t & 7;
    const short* vg = &VT[((size_t)bh * DH + vrow) * NPOS + ((vblk ^ (vrow & 7)) * 8)];

    f32x4 zero = {0.f, 0.f, 0.f, 0.f};
    f32x4 o0 = zero, o1 = zero;
    float ls0 = 0.f, ls1 = 0.f, ls2 = 0.f, ls3 = 0.f;
    short* pw = &p_sm[wid * 1024];
    int rsw = l15 & 7;

    const float LOG2E = 1.4426950408889634f;
    const float MBIAS = -17.312340490667561f;  // -12*log2(e)

    // issue tile 0 into buf 0
    gl_lds16(kg, &k_sm[0][wid * 512]);
    gl_lds16(vg, &vt_sm[0][wid * 512]);

    for (int kt = 0; kt < 36; ++kt) {
        int cur = kt & 1;
        if (kt + 1 < 36) {
            int nkv = (kt + 1) * 64;
            gl_lds16(kg + (size_t)nkv * DH, &k_sm[cur ^ 1][wid * 512]);
            gl_lds16(vg + nkv, &vt_sm[cur ^ 1][wid * 512]);
            asm volatile("s_waitcnt vmcnt(2)" ::: "memory");
        } else {
            asm volatile("s_waitcnt vmcnt(0)" ::: "memory");
        }
        __builtin_amdgcn_s_barrier();

        const short* kb = &k_sm[cur][0];
        const short* vb = &vt_sm[cur][0];

        // S^T = mfma(K, Q): lane holds S[qrow=l15][key = sub*16 + l4*4 + r]
        f32x4 s[4];
#pragma unroll
        for (int sub = 0; sub < 4; ++sub) {
            int key = sub * 16 + l15;
            bf16x8 kf = *(const bf16x8*)&kb[key * 32 + ((l4 ^ ((key >> 1) & 3)) * 8)];
            s[sub] = __builtin_amdgcn_mfma_f32_16x16x32_bf16(kf, qf, zero, 0, 0, 0);
        }

        // p = exp(s - 12); pack bf16 pairs; store 8B to per-wave P_lds
#pragma unroll
        for (int sub = 0; sub < 4; ++sub) {
            float e0 = __expf(fmaf(s[sub][0], LOG2E, MBIAS) * 0.69314718056f);
            float e1 = __expf(fmaf(s[sub][1], LOG2E, MBIAS) * 0.69314718056f);
            float e2 = __expf(fmaf(s[sub][2], LOG2E, MBIAS) * 0.69314718056f);
            float e3 = __expf(fmaf(s[sub][3], LOG2E, MBIAS) * 0.69314718056f);
            ls0 += e0; ls1 += e1; ls2 += e2; ls3 += e3;
            unsigned w0 = cvtpk(e0, e1);
            unsigned w1 = cvtpk(e2, e3);
            int blk = (2 * sub + (l4 >> 1)) ^ rsw;
            *(unsigned long long*)&pw[l15 * 64 + blk * 8 + (l4 & 1) * 4] =
                (unsigned long long)w0 | ((unsigned long long)w1 << 32);
        }

        // O^T += mfma(V^T, P): lane holds O[qrow=l15][d = dtile*16 + l4*4 + r]
#pragma unroll
        for (int kh = 0; kh < 2; ++kh) {
            int pblk = (kh * 4 + l4);
            bf16x8 pf = *(const bf16x8*)&pw[l15 * 64 + ((pblk ^ rsw) * 8)];
            bf16x8 vf0 = *(const bf16x8*)&vb[l15 * 64 + ((pblk ^ (l15 & 7)) * 8)];
            o0 = __builtin_amdgcn_mfma_f32_16x16x32_bf16(vf0, pf, o0, 0, 0, 0);
            int d1 = 16 + l15;
            bf16x8 vf1 = *(const bf16x8*)&vb[d1 * 64 + ((pblk ^ (d1 & 7)) * 8)];
            o1 = __builtin_amdgcn_mfma_f32_16x16x32_bf16(vf1, pf, o1, 0, 0, 0);
        }
        asm volatile("" ::: "memory");
        __builtin_amdgcn_s_barrier();
    }

    float lsum = (ls0 + ls1) + (ls2 + ls3);
    lsum += __shfl_xor(lsum, 16);
    lsum += __shfl_xor(lsum, 32);
    float inv = 1.0f / lsum;

    int b = bh >> 3, h = bh & 7;
    size_t obase = ((size_t)b * NPOS + qrow) * EMBED + h * DH;
    unsigned a0 = cvtpk(o0[0] * inv, o0[1] * inv);
    unsigned a1 = cvtpk(o0[2] * inv, o0[3] * inv);
    *(unsigned long long*)&AO[obase + l4 * 4] =
        (unsigned long long)a0 | ((unsigned long long)a1 << 32);
    unsigned b0 = cvtpk(o1[0] * inv, o1[1] * inv);
    unsigned b1 = cvtpk(o1[2] * inv, o1[3] * inv);
    *(unsigned long long*)&AO[obase + 16 + l4 * 4] =
        (unsigned long long)b0 | ((unsigned long long)b1 << 32);
}

// ---------------- kernel 5: out projection + transpose ----------------
__global__ __launch_bounds__(256) void gemm_out(
        const short* __restrict__ A, const short* __restrict__ B,
        const float* __restrict__ bo, float* __restrict__ out) {
    __shared__ short a_sm[128 * 32];
    __shared__ short b_sm[128 * 32];
    int bx = blockIdx.x;
    int bm = bx / 2, bn = bx % 2;
    int m0 = bm * 128, n0 = bn * 128;
    int t = threadIdx.x;
    int lane = t & 63, wid = t >> 6;
    int wm = wid >> 1, wn = wid & 1;
    int l15 = lane & 15, l4 = lane >> 4;

    f32x4 zero = {0.f, 0.f, 0.f, 0.f};
    f32x4 acc[4][4];
#pragma unroll
    for (int mi = 0; mi < 4; ++mi)
#pragma unroll
        for (int ni = 0; ni < 4; ++ni) acc[mi][ni] = zero;

    for (int ks = 0; ks < 8; ++ks) {
        __syncthreads();
#pragma unroll
        for (int pass = 0; pass < 2; ++pass) {
            int idx = t + pass * 256;
            int row = idx >> 2, slot = idx & 3;
            int sw = slot ^ ((row >> 1) & 3);
            *(bf16x8*)&a_sm[row * 32 + sw * 8] =
                *(const bf16x8*)&A[(size_t)(m0 + row) * 256 + ks * 32 + slot * 8];
            *(bf16x8*)&b_sm[row * 32 + sw * 8] =
                *(const bf16x8*)&B[(size_t)(n0 + row) * 256 + ks * 32 + slot * 8];
        }
        __syncthreads();
        bf16x8 af[4], bfr[4];
#pragma unroll
        for (int mi = 0; mi < 4; ++mi) {
            int ar = wm * 64 + mi * 16 + l15;
            af[mi] = *(const bf16x8*)&a_sm[ar * 32 + ((l4 ^ ((ar >> 1) & 3)) * 8)];
        }
#pragma unroll
        for (int ni = 0; ni < 4; ++ni) {
            int br = wn * 64 + ni * 16 + l15;
            bfr[ni] = *(const bf16x8*)&b_sm[br * 32 + ((l4 ^ ((br >> 1) & 3)) * 8)];
        }
#pragma unroll
        for (int mi = 0; mi < 4; ++mi)
#pragma unroll
            for (int ni = 0; ni < 4; ++ni)
                acc[mi][ni] = __builtin_amdgcn_mfma_f32_16x16x32_bf16(
                    af[mi], bfr[ni], acc[mi][ni], 0, 0, 0);
    }

#pragma unroll
    for (int mi = 0; mi < 4; ++mi) {
        int rowb = m0 + wm * 64 + mi * 16 + l4 * 4;
        int b = rowb / NPOS;
        int pos = rowb - b * NPOS;
#pragma unroll
        for (int ni = 0; ni < 4; ++ni) {
            int jcol = n0 + wn * 64 + ni * 16 + l15;
            float bias = bo[jcol];
            f32x4 v;
#pragma unroll
            for (int r = 0; r < 4; ++r) v[r] = acc[mi][ni][r] + bias;
            *(f32x4*)&out[((size_t)(b * EMBED) + jcol) * NPOS + pos] = v;
        }
    }
}

extern "C" void kernel_launch(void* const* d_in, const int* in_sizes, int n_in,
                              void* d_out, int out_size, void* d_ws, size_t ws_size,
                              hipStream_t stream) {
    const float* x  = (const float*)d_in[0];
    const float* wq = (const float*)d_in[1];
    const float* bq = (const float*)d_in[2];
    const float* wk = (const float*)d_in[3];
    const float* bk = (const float*)d_in[4];
    const float* wv = (const float*)d_in[5];
    const float* bv = (const float*)d_in[6];
    const float* wo = (const float*)d_in[7];
    const float* bo = (const float*)d_in[8];

    char* ws = (char*)d_ws;
    short* wqkv = (short*)(ws);               // 768*256*2   = 393216
    short* wob  = (short*)(ws + 393216);      // 256*256*2   = 131072
    short* xs   = (short*)(ws + 524288);      // 9216*256*2  = 4718592
    short* qb   = (short*)(ws + 5242880);     // 4718592
    short* kb   = (short*)(ws + 9961472);     // 4718592
    short* vtb  = (short*)(ws + 14680064);    // 4718592
    short* ao   = (short*)(ws + 19398656);    // 4718592 -> total 24117248
    float* out  = (float*)d_out;

    hipLaunchKernelGGL(prep_weights, dim3(1024), dim3(256), 0, stream, wq, wk, wv, wo, wqkv, wob);
    hipLaunchKernelGGL(build_xs,     dim3(1152), dim3(256), 0, stream, x, xs);
    hipLaunchKernelGGL(gemm_qkv,     dim3(432),  dim3(256), 0, stream, xs, wqkv, bq, bk, bv, qb, kb, vtb);
    hipLaunchKernelGGL(attn_fwd,     dim3(1152), dim3(256), 0, stream, qb, kb, vtb, ao);
    hipLaunchKernelGGL(gemm_out,     dim3(144),  dim3(256), 0, stream, ao, wob, bo, out);
}

// Round 3
// 90.948 us; speedup vs baseline: 1.9045x; 1.0553x over previous
//
#include <hip/hip_runtime.h>

#define EMBED 256
#define NPOS  2304   // 48*48
#define BATCH 4
#define NH    8
#define DH    32

typedef float f32x4  __attribute__((ext_vector_type(4)));
typedef short bf16x8 __attribute__((ext_vector_type(8)));
typedef short s16x4  __attribute__((ext_vector_type(4)));
typedef unsigned u32x4 __attribute__((ext_vector_type(4)));

static __device__ __forceinline__ short f2b(float f) {
    union { float f; unsigned u; } c; c.f = f;
    unsigned r = (c.u + 0x7FFFu + ((c.u >> 16) & 1u)) >> 16;
    return (short)r;
}

static __device__ __forceinline__ unsigned cvtpk(float lo, float hi) {
    unsigned r;
    asm("v_cvt_pk_bf16_f32 %0, %1, %2" : "=v"(r) : "v"(lo), "v"(hi));
    return r;
}

static __device__ __forceinline__ float fexp2(float x) {
    float r;
    asm("v_exp_f32 %0, %1" : "=v"(r) : "v"(x));
    return r;
}

static __device__ __forceinline__ void plswap32(unsigned& a, unsigned& b) {
    asm("v_permlane32_swap_b32 %0, %1" : "+v"(a), "+v"(b));
}
static __device__ __forceinline__ void plswap16(unsigned& a, unsigned& b) {
    asm("v_permlane16_swap_b32 %0, %1" : "+v"(a), "+v"(b));
}

static __device__ __forceinline__ void gl_lds16(const short* g, short* l) {
    __builtin_amdgcn_global_load_lds(
        (const __attribute__((address_space(1))) unsigned int*)(g),
        (__attribute__((address_space(3))) unsigned int*)(l),
        16, 0, 0);
}

// ---------------- kernel 1: weights->bf16 AND xs = transpose(x)+PE ----------------
__global__ __launch_bounds__(256) void prep_all(
        const float* __restrict__ x,
        const float* __restrict__ wq, const float* __restrict__ wk,
        const float* __restrict__ wv, const float* __restrict__ wo,
        short* __restrict__ wqkv, short* __restrict__ wob,
        short* __restrict__ xs) {
    __shared__ float xt[32][65];
    int blk = blockIdx.x;
    int t = threadIdx.x;
    if (blk < 1024) {
        int g = blk * 256 + t;
        if (g < 196608) {
            int j = g >> 8, kk = g & 255;
            int proj = j >> 8, jj = j & 255;
            const float* s = (proj == 0) ? wq : (proj == 1) ? wk : wv;
            wqkv[g] = f2b(s[jj * 256 + kk]);
        } else if (g < 262144) {
            int h2 = g - 196608;
            wob[h2] = f2b(wo[h2]);
        }
        return;
    }
    int bx = blk - 1024;
    int b = bx / 288, rem = bx % 288;
    int c0 = (rem / 36) * 32, pos0 = (rem % 36) * 64;
    int j = t & 63, i0 = t >> 6;
    const float* xp = x + (size_t)(b * EMBED + c0) * NPOS + pos0;
#pragma unroll
    for (int rr = 0; rr < 8; ++rr) {
        int i = rr * 4 + i0;
        xt[i][j] = xp[(size_t)i * NPOS + j];
    }
    __syncthreads();
    int ii = (t & 15) * 2, jj0 = t >> 4;
    const float kln = -0.07195578415606394f;  // -ln(10000)/128
#pragma unroll
    for (int pp = 0; pp < 4; ++pp) {
        int jj = pp * 16 + jj0;
        int pos = pos0 + jj;
        float v0 = xt[ii][jj], v1 = xt[ii + 1][jj];
        float pe0 = 0.f, pe1 = 0.f;
        if (pos > 0) {
            int c = c0 + ii;
            float a0 = (float)pos * __expf((float)c * kln);
            float a1 = (float)pos * __expf((float)(c + 1) * kln);
            pe0 = __sinf(a0);   // even col -> sin
            pe1 = __cosf(a1);   // odd col -> cos
        }
        unsigned lo = (unsigned short)f2b(v0 + pe0);
        unsigned hi = (unsigned short)f2b(v1 + pe1);
        *reinterpret_cast<unsigned*>(xs + (size_t)(b * NPOS + pos) * EMBED + c0 + ii) =
            lo | (hi << 16);
    }
}

// ---------------- kernel 2: QKV GEMM (64x64 tiles, bias in C-init) ----------------
// A = xs bf16 [9216][256], B = wqkv bf16 [768][256]
// q (scaled log2e/sqrt(dh)), k, vt[b][h][dh][n], all bf16
__global__ __launch_bounds__(256) void gemm_qkv(
        const short* __restrict__ A, const short* __restrict__ Bw,
        const float* __restrict__ bq, const float* __restrict__ bk,
        const float* __restrict__ bv,
        short* __restrict__ qd, short* __restrict__ kd, short* __restrict__ vtd) {
    __shared__ short a_sm[64 * 32];
    __shared__ short b_sm[64 * 32];
    int bx = blockIdx.x;            // 144 x 12
    int bm = bx / 12, bn = bx % 12;
    int m0 = bm * 64, n0 = bn * 64;
    int t = threadIdx.x;
    int lane = t & 63, wid = t >> 6;
    int wm = wid >> 1, wn = wid & 1;
    int l15 = lane & 15, l4 = lane >> 4;

    f32x4 acc[2][2];
#pragma unroll
    for (int ni = 0; ni < 2; ++ni) {
        int jcol = n0 + wn * 32 + ni * 16 + l15;
        int proj = jcol >> 8, jj = jcol & 255;
        float bias = ((proj == 0) ? bq : (proj == 1) ? bk : bv)[jj];
        f32x4 bi = {bias, bias, bias, bias};
        acc[0][ni] = bi;
        acc[1][ni] = bi;
    }

    int srow = t >> 2, sblk = t & 3;
    int ssw = (sblk ^ ((srow >> 1) & 3)) * 8;
    const short* ag = &A[(size_t)(m0 + srow) * 256 + sblk * 8];
    const short* bg = &Bw[(size_t)(n0 + srow) * 256 + sblk * 8];
    short* al = &a_sm[srow * 32 + ssw];
    short* bl = &b_sm[srow * 32 + ssw];

    for (int ks = 0; ks < 8; ++ks) {
        __syncthreads();
        *(bf16x8*)al = *(const bf16x8*)(ag + ks * 32);
        *(bf16x8*)bl = *(const bf16x8*)(bg + ks * 32);
        __syncthreads();
        bf16x8 af[2], bf[2];
#pragma unroll
        for (int mi = 0; mi < 2; ++mi) {
            int ar = wm * 32 + mi * 16 + l15;
            af[mi] = *(const bf16x8*)&a_sm[ar * 32 + ((l4 ^ ((ar >> 1) & 3)) * 8)];
        }
#pragma unroll
        for (int ni = 0; ni < 2; ++ni) {
            int br = wn * 32 + ni * 16 + l15;
            bf[ni] = *(const bf16x8*)&b_sm[br * 32 + ((l4 ^ ((br >> 1) & 3)) * 8)];
        }
#pragma unroll
        for (int mi = 0; mi < 2; ++mi)
#pragma unroll
            for (int ni = 0; ni < 2; ++ni)
                acc[mi][ni] = __builtin_amdgcn_mfma_f32_16x16x32_bf16(
                    af[mi], bf[ni], acc[mi][ni], 0, 0, 0);
    }

    const float qs = 0.2550348623f;  // log2(e)/sqrt(32)
#pragma unroll
    for (int mi = 0; mi < 2; ++mi) {
        int rowb = m0 + wm * 32 + mi * 16 + l4 * 4;
        int b = rowb / NPOS;
        int pos = rowb - b * NPOS;
#pragma unroll
        for (int ni = 0; ni < 2; ++ni) {
            int jcol = n0 + wn * 32 + ni * 16 + l15;
            int proj = jcol >> 8, jj = jcol & 255;
            int h = jj >> 5, d = jj & 31;
            if (proj == 2) {
                s16x4 pk;
#pragma unroll
                for (int r = 0; r < 4; ++r) pk[r] = f2b(acc[mi][ni][r]);
                *(s16x4*)&vtd[((size_t)(b * NH + h) * DH + d) * NPOS + pos] = pk;
            } else {
                short* dst = (proj == 0) ? qd : kd;
                float sc = (proj == 0) ? qs : 1.0f;
#pragma unroll
                for (int r = 0; r < 4; ++r)
                    dst[((size_t)(b * NH + h) * NPOS + pos + r) * DH + d] =
                        f2b(acc[mi][ni][r] * sc);
            }
        }
    }
}

// ---------------- kernel 3: flash attention ----------------
// 2 waves x 32 qrows; P stays in registers via permlane swaps; exp2 softmax
// Q,K [bh][n][dh] bf16 (Q pre-scaled by log2e/sqrt(dh)), VT [bh][dh][n] bf16 -> AO [b][n][c] bf16
__global__ __launch_bounds__(128) void attn_fwd(
        const short* __restrict__ Q, const short* __restrict__ K,
        const short* __restrict__ VT, short* __restrict__ AO) {
    __shared__ short k_sm[2][2048];    // [buf][key 64][dh 32], 16B blocks swizzled blk^((key>>1)&3)
    __shared__ short vt_sm[2][2048];   // [buf][d 32][key 64],  16B blocks swizzled blk^(d&7)

    int bx0 = blockIdx.x;
    int bx = (bx0 & 7) * 144 + (bx0 >> 3);   // XCD-contiguous: same bh -> same XCD
    int bh = bx / 36, qt0 = bx % 36;
    int q0 = qt0 * 64;
    int t = threadIdx.x, lane = t & 63, wid = t >> 6;
    int l15 = lane & 15, l4 = lane >> 4;

    // Q B-frags: col(l15)=qrow, k(l4*8..)=dh; qt selects 16-row group
    bf16x8 qf[2];
    {
        const short* qp = &Q[((size_t)bh * NPOS + q0 + wid * 32 + l15) * DH + l4 * 8];
        qf[0] = *(const bf16x8*)qp;
        qf[1] = *(const bf16x8*)(qp + 16 * DH);
    }

    // staging sources (pre-swizzled global addr; LDS dest linear)
    int krow = t >> 2, kblk = t & 3;   // t<128: rows 0..31 (+32 for 2nd chunk)
    const short* kg = &K[((size_t)bh * NPOS + krow) * DH + ((kblk ^ ((krow >> 1) & 3)) * 8)];
    int vrow = t >> 3, vblk = t & 7;   // rows 0..15 (+16)
    const short* vg = &VT[((size_t)bh * DH + vrow) * NPOS + ((vblk ^ (vrow & 7)) * 8)];

    f32x4 zero = {0.f, 0.f, 0.f, 0.f};
    f32x4 o[2][2];                      // [dtile][qt]
    o[0][0] = zero; o[0][1] = zero; o[1][0] = zero; o[1][1] = zero;
    float ls[2] = {0.f, 0.f};
    const float MB = -17.312340490667561f;  // -12*log2(e)
    const f32x4 mb = {MB, MB, MB, MB};

    // issue tile 0 into buf 0
    gl_lds16(kg,              &k_sm[0][wid * 512]);
    gl_lds16(kg + 1024,       &k_sm[0][wid * 512 + 1024]);
    gl_lds16(vg,              &vt_sm[0][wid * 512]);
    gl_lds16(vg + 16 * NPOS,  &vt_sm[0][wid * 512 + 1024]);

    for (int kt = 0; kt < 36; ++kt) {
        int cur = kt & 1;
        if (kt + 1 < 36) {
            size_t ko = (size_t)(kt + 1) * 64 * DH;
            int vo = (kt + 1) * 64;
            gl_lds16(kg + ko,                 &k_sm[cur ^ 1][wid * 512]);
            gl_lds16(kg + ko + 1024,          &k_sm[cur ^ 1][wid * 512 + 1024]);
            gl_lds16(vg + vo,                 &vt_sm[cur ^ 1][wid * 512]);
            gl_lds16(vg + vo + 16 * NPOS,     &vt_sm[cur ^ 1][wid * 512 + 1024]);
            asm volatile("s_waitcnt vmcnt(4)" ::: "memory");
        } else {
            asm volatile("s_waitcnt vmcnt(0)" ::: "memory");
        }
        __builtin_amdgcn_s_barrier();
        asm volatile("" ::: "memory");

        const short* kb = k_sm[cur];
        const short* vb = vt_sm[cur];

        // S^T = mfma(K, Q, MB): lane holds S[key=sub*16+l4*4+r][qrow=qt*16+l15] + MB
        bf16x8 kf[4];
#pragma unroll
        for (int sub = 0; sub < 4; ++sub) {
            int key = sub * 16 + l15;
            kf[sub] = *(const bf16x8*)&kb[key * 32 + ((l4 ^ ((key >> 1) & 3)) * 8)];
        }
        f32x4 s[4][2];
#pragma unroll
        for (int sub = 0; sub < 4; ++sub) {
            s[sub][0] = __builtin_amdgcn_mfma_f32_16x16x32_bf16(kf[sub], qf[0], mb, 0, 0, 0);
            s[sub][1] = __builtin_amdgcn_mfma_f32_16x16x32_bf16(kf[sub], qf[1], mb, 0, 0, 0);
        }

        // p = 2^s (one v_exp each); pack to bf16 pairs
        unsigned pk[4][2][2];
#pragma unroll
        for (int sub = 0; sub < 4; ++sub)
#pragma unroll
            for (int qt = 0; qt < 2; ++qt) {
                float e0 = fexp2(s[sub][qt][0]);
                float e1 = fexp2(s[sub][qt][1]);
                float e2 = fexp2(s[sub][qt][2]);
                float e3 = fexp2(s[sub][qt][3]);
                ls[qt] += (e0 + e1) + (e2 + e3);
                pk[sub][qt][0] = cvtpk(e0, e1);
                pk[sub][qt][1] = cvtpk(e2, e3);
            }

        // Redistribute S^T fragments -> PV B-frags entirely in registers:
        // (U,V) = swap16(swap32(pk[kh*2], pk[kh*2+1])) gives
        // U rows=[A.R0,A.R2,B.R0,B.R2], V=[A.R1,A.R3,B.R1,B.R3]; frag={U0,U1,V0,V1}
        bf16x8 pfr[2][2];
#pragma unroll
        for (int kh = 0; kh < 2; ++kh)
#pragma unroll
            for (int qt = 0; qt < 2; ++qt) {
                unsigned a0 = pk[kh * 2][qt][0], b0 = pk[kh * 2 + 1][qt][0];
                plswap32(a0, b0);
                plswap16(a0, b0);
                unsigned a1 = pk[kh * 2][qt][1], b1 = pk[kh * 2 + 1][qt][1];
                plswap32(a1, b1);
                plswap16(a1, b1);
                u32x4 fr = {a0, a1, b0, b1};
                pfr[kh][qt] = __builtin_bit_cast(bf16x8, fr);
            }

        // O^T += mfma(V^T, P): lane holds O[d=dt*16+l4*4+r][qrow=qt*16+l15]
#pragma unroll
        for (int kh = 0; kh < 2; ++kh)
#pragma unroll
            for (int dt2 = 0; dt2 < 2; ++dt2) {
                int d = dt2 * 16 + l15;
                bf16x8 vf = *(const bf16x8*)&vb[d * 64 + (((kh * 4 + l4) ^ (d & 7)) * 8)];
                o[dt2][0] = __builtin_amdgcn_mfma_f32_16x16x32_bf16(vf, pfr[kh][0], o[dt2][0], 0, 0, 0);
                o[dt2][1] = __builtin_amdgcn_mfma_f32_16x16x32_bf16(vf, pfr[kh][1], o[dt2][1], 0, 0, 0);
            }
        asm volatile("" ::: "memory");
        __builtin_amdgcn_s_barrier();
        asm volatile("" ::: "memory");
    }

    float l0 = ls[0];
    l0 += __shfl_xor(l0, 16);
    l0 += __shfl_xor(l0, 32);
    float l1 = ls[1];
    l1 += __shfl_xor(l1, 16);
    l1 += __shfl_xor(l1, 32);
    float inv0 = __builtin_amdgcn_rcpf(l0);
    float inv1 = __builtin_amdgcn_rcpf(l1);

    int b = bh >> 3, h = bh & 7;
#pragma unroll
    for (int qt = 0; qt < 2; ++qt) {
        int qrow = q0 + wid * 32 + qt * 16 + l15;
        float inv = (qt == 0) ? inv0 : inv1;
        size_t obase = ((size_t)b * NPOS + qrow) * EMBED + h * DH;
#pragma unroll
        for (int dt2 = 0; dt2 < 2; ++dt2) {
            unsigned x0 = cvtpk(o[dt2][qt][0] * inv, o[dt2][qt][1] * inv);
            unsigned x1 = cvtpk(o[dt2][qt][2] * inv, o[dt2][qt][3] * inv);
            *(unsigned long long*)&AO[obase + dt2 * 16 + l4 * 4] =
                (unsigned long long)x0 | ((unsigned long long)x1 << 32);
        }
    }
}

// ---------------- kernel 4: out projection + transpose (32x64 tiles) ----------------
// A = ao bf16 [9216][256], B = wob bf16 [256][256] -> out fp32 [b][c][n]
__global__ __launch_bounds__(256) void gemm_out(
        const short* __restrict__ A, const short* __restrict__ Bw,
        const float* __restrict__ bo, float* __restrict__ out) {
    __shared__ short a_sm[32 * 32];
    __shared__ short b_sm[64 * 32];
    int bx = blockIdx.x;             // 288 x 4
    int bm = bx >> 2, bn = bx & 3;
    int m0 = bm * 32, n0 = bn * 64;
    int t = threadIdx.x;
    int lane = t & 63, wid = t >> 6;
    int wm = wid >> 1, wn = wid & 1;
    int l15 = lane & 15, l4 = lane >> 4;

    f32x4 acc[2];
#pragma unroll
    for (int ni = 0; ni < 2; ++ni) {
        float bias = bo[n0 + wn * 32 + ni * 16 + l15];
        f32x4 bi = {bias, bias, bias, bias};
        acc[ni] = bi;
    }

    int srow = t >> 2, sblk = t & 3;
    int ssw = (sblk ^ ((srow >> 1) & 3)) * 8;
    const short* ag = &A[(size_t)(m0 + srow) * 256 + sblk * 8];
    const short* bg = &Bw[(size_t)(n0 + srow) * 256 + sblk * 8];
    short* al = &a_sm[srow * 32 + ssw];
    short* bl = &b_sm[srow * 32 + ssw];

    for (int ks = 0; ks < 8; ++ks) {
        __syncthreads();
        if (t < 128) *(bf16x8*)al = *(const bf16x8*)(ag + ks * 32);
        *(bf16x8*)bl = *(const bf16x8*)(bg + ks * 32);
        __syncthreads();
        int ar = wm * 16 + l15;
        bf16x8 af = *(const bf16x8*)&a_sm[ar * 32 + ((l4 ^ ((ar >> 1) & 3)) * 8)];
        bf16x8 bf[2];
#pragma unroll
        for (int ni = 0; ni < 2; ++ni) {
            int br = wn * 32 + ni * 16 + l15;
            bf[ni] = *(const bf16x8*)&b_sm[br * 32 + ((l4 ^ ((br >> 1) & 3)) * 8)];
        }
#pragma unroll
        for (int ni = 0; ni < 2; ++ni)
            acc[ni] = __builtin_amdgcn_mfma_f32_16x16x32_bf16(af, bf[ni], acc[ni], 0, 0, 0);
    }

    int rowb = m0 + wm * 16 + l4 * 4;
    int b = rowb / NPOS;
    int pos = rowb - b * NPOS;
#pragma unroll
    for (int ni = 0; ni < 2; ++ni) {
        int jcol = n0 + wn * 32 + ni * 16 + l15;
        *(f32x4*)&out[((size_t)(b * EMBED) + jcol) * NPOS + pos] = acc[ni];
    }
}

extern "C" void kernel_launch(void* const* d_in, const int* in_sizes, int n_in,
                              void* d_out, int out_size, void* d_ws, size_t ws_size,
                              hipStream_t stream) {
    const float* x  = (const float*)d_in[0];
    const float* wq = (const float*)d_in[1];
    const float* bq = (const float*)d_in[2];
    const float* wk = (const float*)d_in[3];
    const float* bk = (const float*)d_in[4];
    const float* wv = (const float*)d_in[5];
    const float* bv = (const float*)d_in[6];
    const float* wo = (const float*)d_in[7];
    const float* bo = (const float*)d_in[8];

    char* ws = (char*)d_ws;
    short* wqkv = (short*)(ws);               // 768*256*2   = 393216
    short* wob  = (short*)(ws + 393216);      // 256*256*2   = 131072
    short* xs   = (short*)(ws + 524288);      // 9216*256*2  = 4718592
    short* qb   = (short*)(ws + 5242880);     // 4718592
    short* kb   = (short*)(ws + 9961472);     // 4718592
    short* vtb  = (short*)(ws + 14680064);    // 4718592
    short* ao   = (short*)(ws + 19398656);    // 4718592 -> total 24117248
    float* out  = (float*)d_out;

    hipLaunchKernelGGL(prep_all, dim3(2176), dim3(256), 0, stream,
                       x, wq, wk, wv, wo, wqkv, wob, xs);
    hipLaunchKernelGGL(gemm_qkv, dim3(1728), dim3(256), 0, stream,
                       xs, wqkv, bq, bk, bv, qb, kb, vtb);
    hipLaunchKernelGGL(attn_fwd, dim3(1152), dim3(128), 0, stream, qb, kb, vtb, ao);
    hipLaunchKernelGGL(gemm_out, dim3(1152), dim3(256), 0, stream, ao, wob, bo, out);
}